// Round 10
// baseline (683.271 us; speedup 1.0000x reference)
//
#include <hip/hip_runtime.h>
#include <stdint.h>

#define NROWS 8192
#define KDIM  1024
#define CAP   512
#define NEGBIG (-9.0e15f)
#define EMIT_THR 16.0f
#define SURV_THR 13.5f
#define MAXS  128

typedef __attribute__((ext_vector_type(8))) __bf16 bf16x8;
typedef __attribute__((ext_vector_type(4))) float f32x4;
typedef __attribute__((ext_vector_type(16))) float f32x16;
typedef __attribute__((ext_vector_type(4))) unsigned short us4;
typedef __attribute__((ext_vector_type(4))) int i32x4;
typedef unsigned short u16;

__device__ __forceinline__ u16 f2bf(float f) {
  unsigned u = __float_as_uint(f);
  u += 0x7fffu + ((u >> 16) & 1u);
  return (u16)(u >> 16);
}
__device__ __forceinline__ float bf2f(u16 h) {
  return __uint_as_float(((unsigned)h) << 16);
}

__device__ __forceinline__ void glds16(const void* g, const char* lds) {
  __builtin_amdgcn_global_load_lds(
      (const __attribute__((address_space(1))) unsigned int*)(uintptr_t)g,
      (__attribute__((address_space(3))) unsigned int*)(uintptr_t)lds, 16, 0, 0);
}

__device__ __forceinline__ f32x4 mfma16(bf16x8 a, bf16x8 b, f32x4 c) {
  return __builtin_amdgcn_mfma_f32_16x16x32_bf16(a, b, c, 0, 0, 0);
}
__device__ __forceinline__ f32x16 mfma32(bf16x8 a, bf16x8 b, f32x16 c) {
  return __builtin_amdgcn_mfma_f32_32x32x16_bf16(a, b, c, 0, 0, 0);
}

// ---------------------------------------------------------------------------
// Pre-GEMM (R4-proven): C[128x128] = A@B^T, split-3 (NSPLIT=3) or 1-pass.
// ---------------------------------------------------------------------------
template<int NSPLIT, bool SPLITOUT>
__global__ __launch_bounds__(512, 1) void gemm_kernel(
    const u16* __restrict__ ah, const u16* __restrict__ al,
    const u16* __restrict__ bh, const u16* __restrict__ bl,
    const float* __restrict__ bias, u16* __restrict__ ch, u16* __restrict__ cl)
{
  extern __shared__ char smem[];
  constexpr int BUFS = (NSPLIT == 3) ? 65536 : 32768;
  constexpr int AHO = 0, ALO = 16384;
  constexpr int BHO = (NSPLIT == 3) ? 32768 : 16384;
  constexpr int BLO = 49152;
  constexpr int NT = KDIM / 64;

  const int tid = threadIdx.x, w = tid >> 6, lane = tid & 63;
  const int wr = w >> 2, wc = w & 3;
  const int bx = blockIdx.x, by = blockIdx.y;
  const int arow0 = bx * 128, bcol0 = by * 128;

  const int srow = w * 16 + (lane >> 3);
  const int scol = ((lane & 7) ^ (lane >> 3)) * 8;
  const size_t sgA = (size_t)(arow0 + srow) * KDIM + scol;
  const size_t sgB = (size_t)(bcol0 + srow) * KDIM + scol;
  const int ldsw = w * 2048;

  auto stg = [&](const u16* src, size_t sg, int kt, int ldsoff) {
    const u16* sp = src + sg + kt * 64;
    glds16(sp,            smem + ldsoff + ldsw);
    glds16(sp + 8 * KDIM, smem + ldsoff + ldsw + 1024);
  };

  const int fa = (wr * 64 + (lane & 15)) * 128;
  const int fb = (wc * 32 + (lane & 15)) * 128;
  const int kqx0 = (((lane >> 4)    ) ^ (lane & 7)) * 16;
  const int kqx1 = (((lane >> 4) + 4) ^ (lane & 7)) * 16;

  stg(ah, sgA, 0, AHO); stg(bh, sgB, 0, BHO);
  if constexpr (NSPLIT == 3) { stg(al, sgA, 0, ALO); stg(bl, sgB, 0, BLO); }
  else { stg(ah, sgA, 1, AHO + BUFS); stg(bh, sgB, 1, BHO + BUFS); }

  f32x4 acc[4][2];
  #pragma unroll
  for (int m = 0; m < 4; ++m) {
    acc[m][0] = f32x4{0.f, 0.f, 0.f, 0.f};
    acc[m][1] = f32x4{0.f, 0.f, 0.f, 0.f};
  }

  for (int t = 0; t < NT; ++t) {
    const int bo  = (t & 1) * BUFS;
    const int bo2 = ((t + 1) & 1) * BUFS;

    if (NSPLIT == 1 && t == NT - 1) asm volatile("s_waitcnt vmcnt(0)" ::: "memory");
    else                            asm volatile("s_waitcnt vmcnt(4)" ::: "memory");
    __builtin_amdgcn_s_barrier();
    __builtin_amdgcn_sched_barrier(0);

    if (NSPLIT == 3 && t + 1 < NT) {
      stg(ah, sgA, t + 1, AHO + bo2);
      stg(bh, sgB, t + 1, BHO + bo2);
    }

    bf16x8 a0[4][2], b0[2][2];
    #pragma unroll
    for (int m = 0; m < 4; ++m) {
      a0[m][0] = *(const bf16x8*)(smem + AHO + bo + fa + m * 2048 + kqx0);
      a0[m][1] = *(const bf16x8*)(smem + AHO + bo + fa + m * 2048 + kqx1);
    }
    #pragma unroll
    for (int n = 0; n < 2; ++n) {
      b0[n][0] = *(const bf16x8*)(smem + BHO + bo + fb + n * 2048 + kqx0);
      b0[n][1] = *(const bf16x8*)(smem + BHO + bo + fb + n * 2048 + kqx1);
    }
    __builtin_amdgcn_s_setprio(1);
    #pragma unroll
    for (int kq = 0; kq < 2; ++kq)
      #pragma unroll
      for (int m = 0; m < 4; ++m)
        #pragma unroll
        for (int n = 0; n < 2; ++n)
          acc[m][n] = mfma16(a0[m][kq], b0[n][kq], acc[m][n]);
    __builtin_amdgcn_s_setprio(0);
    asm volatile("s_waitcnt lgkmcnt(0)" ::: "memory");

    if constexpr (NSPLIT == 3) {
      if (t + 1 < NT) asm volatile("s_waitcnt vmcnt(4)" ::: "memory");
      else            asm volatile("s_waitcnt vmcnt(0)" ::: "memory");
      __builtin_amdgcn_s_barrier();
      __builtin_amdgcn_sched_barrier(0);

      if (t + 1 < NT) {
        stg(al, sgA, t + 1, ALO + bo2);
        stg(bl, sgB, t + 1, BLO + bo2);
      }
      bf16x8 a1[4][2], b1[2][2];
      #pragma unroll
      for (int m = 0; m < 4; ++m) {
        a1[m][0] = *(const bf16x8*)(smem + ALO + bo + fa + m * 2048 + kqx0);
        a1[m][1] = *(const bf16x8*)(smem + ALO + bo + fa + m * 2048 + kqx1);
      }
      #pragma unroll
      for (int n = 0; n < 2; ++n) {
        b1[n][0] = *(const bf16x8*)(smem + BLO + bo + fb + n * 2048 + kqx0);
        b1[n][1] = *(const bf16x8*)(smem + BLO + bo + fb + n * 2048 + kqx1);
      }
      __builtin_amdgcn_s_setprio(1);
      #pragma unroll
      for (int kq = 0; kq < 2; ++kq)
        #pragma unroll
        for (int m = 0; m < 4; ++m)
          #pragma unroll
          for (int n = 0; n < 2; ++n)
            acc[m][n] = mfma16(a1[m][kq], b0[n][kq], acc[m][n]);
      #pragma unroll
      for (int kq = 0; kq < 2; ++kq)
        #pragma unroll
        for (int m = 0; m < 4; ++m)
          #pragma unroll
          for (int n = 0; n < 2; ++n)
            acc[m][n] = mfma16(a0[m][kq], b1[n][kq], acc[m][n]);
      __builtin_amdgcn_s_setprio(0);
      asm volatile("s_waitcnt lgkmcnt(0)" ::: "memory");
    } else {
      __builtin_amdgcn_s_barrier();
      if (t + 2 < NT) {
        stg(ah, sgA, t + 2, AHO + bo);
        stg(bh, sgB, t + 2, BHO + bo);
      }
    }
  }

  const int l15 = lane & 15, g4 = (lane >> 4) << 2;
  const int colb = bcol0 + wc * 32 + l15;
  const float bi0 = bias[colb], bi1 = bias[colb + 16];
  #pragma unroll
  for (int m = 0; m < 4; ++m) {
    #pragma unroll
    for (int j = 0; j < 4; ++j) {
      const int row = arow0 + wr * 64 + m * 16 + g4 + j;
      float v0 = acc[m][0][j] + bi0, v1 = acc[m][1][j] + bi1;
      u16 h0 = f2bf(v0), h1 = f2bf(v1);
      ch[(size_t)row * KDIM + colb] = h0;
      ch[(size_t)row * KDIM + colb + 16] = h1;
      if constexpr (SPLITOUT) {
        cl[(size_t)row * KDIM + colb] = f2bf(v0 - bf2f(h0));
        cl[(size_t)row * KDIM + colb + 16] = f2bf(v1 - bf2f(h1));
      }
    }
  }
}

// ---------------------------------------------------------------------------
// Scores sweep R10 — 32x32x16 MFMA (2495 TF ceiling, half the instructions).
// 256x256 tile, BK=64, 2x64KB dbuf, R6/R9-proven LDS layout (128B rows,
// slot = kq ^ (row&7); staging identical to R9, 0 conflicts measured).
// Wave tile 128x64 = 4x2 blocks of 32x32; acc[4][2] f32x16.
// Frag reads: A row=lane&31 (+mb*32+wr*128), k-half=lane>>5 -> slot
//   ks*2+h ^ (lane&7); analytically bank-balanced (8 lanes/16B-slot).
// Per K-tile: 24 ds_read_b128, 32 MFMA, 2 barriers, counted vmcnt(8)
//   (stage(t) retires exactly, stage(t+1) stays in flight; 0 only at tail).
// stage(t+2) issued after the read-drain barrier (WAR airtight).
// Mapping: R6's (XCD hosts 4 A-slabs = 2MB L2-fit; 8 siblings/slab).
// Epilogue: m74/m101-verified 32x32 C layout (col=lane&31,
//   row=(reg&3)+8*(reg>>2)+4*(lane>>5)); bounded emission unchanged.
// ---------------------------------------------------------------------------
__global__ __launch_bounds__(512, 2) void scores_kernel(
    const u16* __restrict__ fh, const u16* __restrict__ gh,
    const uint32_t* __restrict__ adjb, uint32_t* __restrict__ cand,
    int* __restrict__ cnts, int* rowmax)
{
  extern __shared__ char smem[];
  constexpr int NT = 64;                 // 4 key-tiles x 16 K-tiles

  const int tid = threadIdx.x, w = tid >> 6, lane = tid & 63;
  const int wr = w >> 2, wc = w & 3;
  const int l31 = lane & 31, hh = lane >> 5;

  const int xcd = blockIdx.x & 7, idx = blockIdx.x >> 3;
  const int bx  = xcd * 4 + (idx & 3);   // 4 A-slabs per XCD (L2-resident)
  const int sub = idx >> 2;              // sibling 0..7 -> key panels {sub+8it}
  const int arow0 = bx * 256;

  // ---- staging (R9-identical): cell=tid -> row=tid>>3, slot=tid&7,
  //      content kq = slot ^ (row&7) from the matching global column.
  const int srow = tid >> 3;
  const int skq  = (tid & 7) ^ (srow & 7);
  const int sdw  = w * 1024;

  auto stageA = [&](int T, int half) {
    char* d = smem + (T & 1) * 65536 + half * 16384 + sdw;
    const u16* s = fh + (size_t)(arow0 + half * 128 + srow) * KDIM
                      + (T & 15) * 64 + skq * 8;
    glds16(s, d);
    glds16(s + (size_t)64 * KDIM, d + 8192);
  };
  auto stageB = [&](int T, int half) {
    char* d = smem + (T & 1) * 65536 + 32768 + half * 16384 + sdw;
    const u16* s = gh + (size_t)((sub + 8 * (T >> 4)) * 256 + half * 128 + srow) * KDIM
                      + (T & 15) * 64 + skq * 8;
    glds16(s, d);
    glds16(s + (size_t)64 * KDIM, d + 8192);
  };

  // ---- fragment read offsets (row&7 == lane&7 since block bases %8==0)
  const int kx[4] = { ((0 + hh) ^ (lane & 7)) * 16, ((2 + hh) ^ (lane & 7)) * 16,
                      ((4 + hh) ^ (lane & 7)) * 16, ((6 + hh) ^ (lane & 7)) * 16 };
  const int abase = (wr * 128 + l31) * 128;           // + mb*4096
  const int bbase = 32768 + (wc * 64 + l31) * 128;    // + nb*4096

  f32x16 acc[4][2];
  #pragma unroll
  for (int mb = 0; mb < 4; ++mb)
    #pragma unroll
    for (int nb = 0; nb < 2; ++nb)
      #pragma unroll
      for (int r = 0; r < 16; ++r) acc[mb][nb][r] = 0.f;

  const unsigned long long lmask = (1ull << lane) - 1ull;
  const unsigned long long halfmask = 0xFFFFFFFFull << (lane & 32);

  // ---- prologue: stage tiles 0 and 1 (16 glds in flight)
  stageA(0, 0); stageA(0, 1); stageB(0, 0); stageB(0, 1);
  stageA(1, 0); stageA(1, 1); stageB(1, 0); stageB(1, 1);

  for (int t = 0; t < NT; ++t) {
    // counted: retires stage(t) exactly; stage(t+1) remains in flight
    if (t == NT - 1) asm volatile("s_waitcnt vmcnt(0)" ::: "memory");
    else             asm volatile("s_waitcnt vmcnt(8)" ::: "memory");
    __builtin_amdgcn_s_barrier();
    __builtin_amdgcn_sched_barrier(0);

    const char* sb = smem + (t & 1) * 65536;
    __builtin_amdgcn_s_setprio(1);
    #pragma unroll
    for (int ks = 0; ks < 4; ++ks) {
      bf16x8 a[4], b[2];
      #pragma unroll
      for (int mb = 0; mb < 4; ++mb)
        a[mb] = *(const bf16x8*)(sb + abase + mb * 4096 + kx[ks]);
      #pragma unroll
      for (int nb = 0; nb < 2; ++nb)
        b[nb] = *(const bf16x8*)(sb + bbase + nb * 4096 + kx[ks]);
      #pragma unroll
      for (int mb = 0; mb < 4; ++mb)
        #pragma unroll
        for (int nb = 0; nb < 2; ++nb)
          acc[mb][nb] = mfma32(a[mb], b[nb], acc[mb][nb]);
    }
    __builtin_amdgcn_s_setprio(0);
    asm volatile("s_waitcnt lgkmcnt(0)" ::: "memory");
    __builtin_amdgcn_sched_barrier(0);
    __builtin_amdgcn_s_barrier();

    if ((t & 15) == 15) {
      // ---- key-tile epilogue: mask, row max, bounded emission (32x32 layout)
      const int it = t >> 4;
      const int bcol0 = (sub + 8 * it) * 256;
      const int cg0 = (bcol0 >> 5) + wc * 2;
      const int k0 = bcol0 + wc * 64 + l31;
      #pragma unroll
      for (int mb = 0; mb < 4; ++mb) {
        #pragma unroll
        for (int r = 0; r < 16; ++r) {
          const int row = arow0 + wr * 128 + mb * 32 + (r & 3) + 8 * (r >> 2) + 4 * hh;
          const uint32_t aw0 = adjb[(size_t)row * (NROWS / 32) + cg0];
          const uint32_t aw1 = adjb[(size_t)row * (NROWS / 32) + cg0 + 1];
          float v0 = fmaxf(acc[mb][0][r], 0.f);
          float v1 = fmaxf(acc[mb][1][r], 0.f);
          float s0 = ((aw0 >> l31) & 1u) ? v0 : NEGBIG;
          float s1 = ((aw1 >> l31) & 1u) ? v1 : NEGBIG;
          float rm = fmaxf(s0, s1);                   // max over 32 cols (own half)
          rm = fmaxf(rm, __shfl_xor(rm, 1));
          rm = fmaxf(rm, __shfl_xor(rm, 2));
          rm = fmaxf(rm, __shfl_xor(rm, 4));
          rm = fmaxf(rm, __shfl_xor(rm, 8));
          rm = fmaxf(rm, __shfl_xor(rm, 16));
          const float old = __int_as_float(rowmax[row]);   // stale-tolerant
          const float mr = fmaxf(rm, old);
          if (l31 == 0 && rm > old) atomicMax(rowmax + row, __float_as_int(rm));
          const float thr = mr - EMIT_THR;
          bool e0 = s0 > thr, e1 = s1 > thr;
          unsigned long long m0 = __ballot(e0), m1 = __ballot(e1);
          int n0 = __popcll(m0 & halfmask), n1 = __popcll(m1 & halfmask);
          int base = 0;
          if (l31 == 0 && (n0 + n1) > 0) base = atomicAdd(cnts + row, n0 + n1);
          base = __shfl(base, lane & 32);
          int p0 = base + __popcll(m0 & halfmask & lmask);
          int p1 = base + n0 + __popcll(m1 & halfmask & lmask);
          if (e0 && p0 < CAP)
            cand[(size_t)row * CAP + p0] = ((uint32_t)f2bf(s0) << 16) | (uint32_t)k0;
          if (e1 && p1 < CAP)
            cand[(size_t)row * CAP + p1] = ((uint32_t)f2bf(s1) << 16) | (uint32_t)(k0 + 32);
          acc[mb][0][r] = 0.f; acc[mb][1][r] = 0.f;
        }
      }
    }

    // stage(t+2) into buf[t&1] — all waves' reads drained by the barrier above
    if (t + 2 < NT) {
      stageA(t + 2, 0); stageA(t + 2, 1);
      stageB(t + 2, 0); stageB(t + 2, 1);
    }
  }
}

// ---------------------------------------------------------------------------
// adj (int32 0/1, 268 MB) -> bitmask (8 MB). BW-bound single pass.
// ---------------------------------------------------------------------------
__global__ __launch_bounds__(256) void adjpack_kernel(
    const int* __restrict__ adj, uint32_t* __restrict__ adjb)
{
  size_t w = (size_t)blockIdx.x * 256 + threadIdx.x;
  const int* src = adj + (w << 5);
  uint32_t m = 0;
  #pragma unroll
  for (int j = 0; j < 8; ++j) {
    i32x4 v = *(const i32x4*)(src + j * 4);
    m |= (v[0] > 0 ? 1u : 0u) << (j * 4)
       | (v[1] > 0 ? 1u : 0u) << (j * 4 + 1)
       | (v[2] > 0 ? 1u : 0u) << (j * 4 + 2)
       | (v[3] > 0 ? 1u : 0u) << (j * 4 + 3);
  }
  adjb[w] = m;
}

// ---------------------------------------------------------------------------
// Finalize: survivors (within SURV_THR of approx max) rescored exactly in
// fp32 from (fh+fl, gh+gl); tail stays approx in the denominator only.
// ---------------------------------------------------------------------------
__global__ __launch_bounds__(256) void finalize_kernel(
    const uint32_t* __restrict__ cand, const int* __restrict__ cnts,
    const u16* __restrict__ fh, const u16* __restrict__ fl,
    const u16* __restrict__ gh, const u16* __restrict__ gl,
    const u16* __restrict__ vh, float* __restrict__ out)
{
  const int row = blockIdx.x, tid = threadIdx.x, wv = tid >> 6, lane = tid & 63;
  __shared__ float sS[CAP];
  __shared__ int sK[CAP];
  __shared__ float sF[KDIM];
  __shared__ float sEx[MAXS];
  __shared__ int sKs[MAXS];
  __shared__ float red[4];
  __shared__ int nsig;
  int cnt = cnts[row]; cnt = cnt < CAP ? cnt : CAP;
  const int col = tid * 4;
  if (cnt <= 0) {
    f32x4 z = {0.f, 0.f, 0.f, 0.f};
    *(f32x4*)(out + (size_t)row * KDIM + col) = z;
    return;
  }
  if (tid == 0) nsig = 0;
  {
    us4 h = *(const us4*)(fh + (size_t)row * KDIM + col);
    us4 l = *(const us4*)(fl + (size_t)row * KDIM + col);
    #pragma unroll
    for (int j = 0; j < 4; ++j) sF[col + j] = bf2f(h[j]) + bf2f(l[j]);
  }
  for (int i = tid; i < cnt; i += 256) {
    uint32_t pk = cand[(size_t)row * CAP + i];
    sS[i] = bf2f((u16)(pk >> 16));
    sK[i] = (int)(pk & 0xFFFFu);
  }
  __syncthreads();
  float lm = NEGBIG;
  for (int i = tid; i < cnt; i += 256) lm = fmaxf(lm, sS[i]);
  #pragma unroll
  for (int d = 1; d < 64; d <<= 1) lm = fmaxf(lm, __shfl_xor(lm, d));
  if ((tid & 63) == 0) red[tid >> 6] = lm;
  __syncthreads();
  const float am = fmaxf(fmaxf(red[0], red[1]), fmaxf(red[2], red[3]));
  __syncthreads();
  for (int i = tid; i < cnt; i += 256) {
    if (sS[i] > am - SURV_THR) {
      int p = atomicAdd(&nsig, 1);
      if (p < MAXS) { sKs[p] = sK[i]; sS[i] = NEGBIG; }
    }
  }
  __syncthreads();
  const int ns = nsig < MAXS ? nsig : MAXS;
  for (int si = wv; si < ns; si += 4) {
    const int key = sKs[si];
    const u16* grh = gh + (size_t)key * KDIM + lane * 16;
    const u16* grl = gl + (size_t)key * KDIM + lane * 16;
    float d = 0.f;
    #pragma unroll
    for (int u = 0; u < 4; ++u) {
      us4 h = *(const us4*)(grh + u * 4);
      us4 l = *(const us4*)(grl + u * 4);
      #pragma unroll
      for (int j = 0; j < 4; ++j)
        d += (bf2f(h[j]) + bf2f(l[j])) * sF[lane * 16 + u * 4 + j];
    }
    #pragma unroll
    for (int dd = 1; dd < 64; dd <<= 1) d += __shfl_xor(d, dd);
    if (lane == 0) sEx[si] = fmaxf(d, 0.f);
  }
  __syncthreads();
  float em = NEGBIG;
  for (int i = tid; i < ns; i += 256) em = fmaxf(em, sEx[i]);
  #pragma unroll
  for (int d = 1; d < 64; d <<= 1) em = fmaxf(em, __shfl_xor(em, d));
  if ((tid & 63) == 0) red[tid >> 6] = em;
  __syncthreads();
  const float m = fmaxf(fmaxf(red[0], red[1]), fmaxf(red[2], red[3]));
  __syncthreads();
  float ls = 0.f;
  for (int i = tid; i < cnt; i += 256) {
    float s = sS[i];
    if (s > NEGBIG * 0.5f) ls += __expf(s - m);
  }
  for (int i = tid; i < ns; i += 256) ls += __expf(sEx[i] - m);
  #pragma unroll
  for (int d = 1; d < 64; d <<= 1) ls += __shfl_xor(ls, d);
  if ((tid & 63) == 0) red[tid >> 6] = ls;
  __syncthreads();
  const float inv = 1.f / (red[0] + red[1] + red[2] + red[3]);
  float a0 = 0.f, a1 = 0.f, a2 = 0.f, a3 = 0.f;
  const u16* vbase = vh + col;
  for (int i = 0; i < ns; ++i) {
    const float wt = __expf(sEx[i] - m) * inv;
    us4 vv = *(const us4*)(vbase + (size_t)sKs[i] * KDIM);
    a0 += wt * bf2f(vv[0]); a1 += wt * bf2f(vv[1]);
    a2 += wt * bf2f(vv[2]); a3 += wt * bf2f(vv[3]);
  }
  f32x4 o = {a0, a1, a2, a3};
  *(f32x4*)(out + (size_t)row * KDIM + col) = o;
}

// ---------------------------------------------------------------------------
// Transpose + hi/lo split of a [K][N] fp32 weight into [N][K] bf16 pair.
// ---------------------------------------------------------------------------
__global__ __launch_bounds__(256) void wsplit_kernel(
    const float* __restrict__ W, u16* __restrict__ th, u16* __restrict__ tl)
{
  __shared__ float tile[32][33];
  const int bx = blockIdx.x, by = blockIdx.y;
  const int tx = threadIdx.x & 31, ty = threadIdx.x >> 5;
  #pragma unroll
  for (int i = 0; i < 4; ++i) {
    int ky = ty + i * 8;
    tile[ky][tx] = W[(size_t)(by * 32 + ky) * KDIM + bx * 32 + tx];
  }
  __syncthreads();
  #pragma unroll
  for (int i = 0; i < 4; ++i) {
    int ny = ty + i * 8;
    float v = tile[tx][ny];
    u16 h = f2bf(v);
    th[(size_t)(bx * 32 + ny) * KDIM + by * 32 + tx] = h;
    tl[(size_t)(bx * 32 + ny) * KDIM + by * 32 + tx] = f2bf(v - bf2f(h));
  }
}

__global__ __launch_bounds__(256) void xsplit_kernel(
    const float* __restrict__ x, u16* __restrict__ xh, u16* __restrict__ xl)
{
  size_t i = ((size_t)blockIdx.x * 256 + threadIdx.x) * 4;
  f32x4 v = *(const f32x4*)(x + i);
  us4 h, l;
  #pragma unroll
  for (int j = 0; j < 4; ++j) {
    h[j] = f2bf(v[j]);
    l[j] = f2bf(v[j] - bf2f(h[j]));
  }
  *(us4*)(xh + i) = h;
  *(us4*)(xl + i) = l;
}

__global__ void ws_report(float* out, size_t n, float v) {
  for (size_t i = (size_t)blockIdx.x * blockDim.x + threadIdx.x; i < n;
       i += (size_t)gridDim.x * blockDim.x) out[i] = v;
}

extern "C" void kernel_launch(void* const* d_in, const int* in_sizes, int n_in,
                              void* d_out, int out_size, void* d_ws, size_t ws_size,
                              hipStream_t stream) {
  (void)in_sizes; (void)n_in;
  const float* x   = (const float*)d_in[0];
  const int*   adj = (const int*)d_in[1];
  const float* Wf  = (const float*)d_in[2];
  const float* bf_ = (const float*)d_in[3];
  const float* Wg  = (const float*)d_in[4];
  const float* bg_ = (const float*)d_in[5];
  const float* W   = (const float*)d_in[6];
  const float* bW_ = (const float*)d_in[7];

  char* p = (char*)d_ws;
  const size_t ND2 = (size_t)NROWS * KDIM * 2;
  const size_t W2  = (size_t)KDIM * KDIM * 2;
  u16* xh = (u16*)p;  p += ND2;
  u16* xl = (u16*)p;  p += ND2;
  u16* fh = (u16*)p;  p += ND2;
  u16* fl = (u16*)p;  p += ND2;
  u16* gh = (u16*)p;  p += ND2;
  u16* gl = (u16*)p;  p += ND2;
  u16* vh = (u16*)p;  p += ND2;
  u16* wfh = (u16*)p; p += W2;
  u16* wfl = (u16*)p; p += W2;
  u16* wgh = (u16*)p; p += W2;
  u16* wgl = (u16*)p; p += W2;
  u16* wh  = (u16*)p; p += W2;
  u16* wl  = (u16*)p; p += W2;
  uint32_t* cand = (uint32_t*)p; p += (size_t)NROWS * CAP * 4;
  int* cnts   = (int*)p; p += (size_t)NROWS * 4;
  int* rowmax = (int*)p; p += (size_t)NROWS * 4;
  const size_t need = (size_t)(p - (char*)d_ws);
  if (ws_size < need) {
    ws_report<<<256, 256, 0, stream>>>((float*)d_out, (size_t)out_size, (float)ws_size);
    return;
  }
  uint32_t* adjb = (uint32_t*)xl;   // aliases xl after pre-GEMMs are done

  auto kf = gemm_kernel<3, true>;
  auto kv = gemm_kernel<1, false>;
  hipFuncSetAttribute((const void*)kf, hipFuncAttributeMaxDynamicSharedMemorySize, 131072);
  hipFuncSetAttribute((const void*)kv, hipFuncAttributeMaxDynamicSharedMemorySize, 65536);
  hipFuncSetAttribute((const void*)scores_kernel, hipFuncAttributeMaxDynamicSharedMemorySize, 131072);

  hipMemsetAsync(cnts, 0, (size_t)NROWS * 8, stream);   // cnts + rowmax (0 == 0.0f)
  wsplit_kernel<<<dim3(32, 32), 256, 0, stream>>>(Wf, wfh, wfl);
  wsplit_kernel<<<dim3(32, 32), 256, 0, stream>>>(Wg, wgh, wgl);
  wsplit_kernel<<<dim3(32, 32), 256, 0, stream>>>(W, wh, wl);
  xsplit_kernel<<<(NROWS * KDIM) / (256 * 4), 256, 0, stream>>>(x, xh, xl);

  // f = x@Wf + bf, g = x@Wg + bg (split-3, hi+lo out), v = x@W + bW (1 pass)
  kf<<<dim3(64, 8), 512, 131072, stream>>>(xh, xl, wfh, wfl, bf_, fh, fl);
  kf<<<dim3(64, 8), 512, 131072, stream>>>(xh, xl, wgh, wgl, bg_, gh, gl);
  kv<<<dim3(64, 8), 512, 65536, stream>>>(xh, xl, wh, wl, bW_, vh, nullptr);
  adjpack_kernel<<<(NROWS * (NROWS / 32)) / 256, 256, 0, stream>>>(adj, adjb);
  // 32x32-MFMA 256x256 scores sweep + bounded candidate emission
  scores_kernel<<<dim3(256), 512, 131072, stream>>>(fh, gh, adjb, cand, cnts, rowmax);
  // exact rescoring of survivors + softmax + v gather
  finalize_kernel<<<NROWS, 256, 0, stream>>>(cand, cnts, fh, fl, gh, gl, vh,
                                             (float*)d_out);
}

// Round 11
// 565.709 us; speedup vs baseline: 1.2078x; 1.2078x over previous
//
#include <hip/hip_runtime.h>
#include <stdint.h>

#define NROWS 8192
#define KDIM  1024
#define CAP   512
#define NEGBIG (-9.0e15f)
#define EMIT_THR 16.0f
#define SURV_THR 13.5f
#define MAXS  128

typedef __attribute__((ext_vector_type(8))) __bf16 bf16x8;
typedef __attribute__((ext_vector_type(4))) float f32x4;
typedef __attribute__((ext_vector_type(4))) unsigned short us4;
typedef __attribute__((ext_vector_type(4))) int i32x4;
typedef unsigned short u16;

__device__ __forceinline__ u16 f2bf(float f) {
  unsigned u = __float_as_uint(f);
  u += 0x7fffu + ((u >> 16) & 1u);
  return (u16)(u >> 16);
}
__device__ __forceinline__ float bf2f(u16 h) {
  return __uint_as_float(((unsigned)h) << 16);
}

__device__ __forceinline__ void glds16(const void* g, const char* lds) {
  __builtin_amdgcn_global_load_lds(
      (const __attribute__((address_space(1))) unsigned int*)(uintptr_t)g,
      (__attribute__((address_space(3))) unsigned int*)(uintptr_t)lds, 16, 0, 0);
}

__device__ __forceinline__ f32x4 mfma16(bf16x8 a, bf16x8 b, f32x4 c) {
  return __builtin_amdgcn_mfma_f32_16x16x32_bf16(a, b, c, 0, 0, 0);
}

// ---------------------------------------------------------------------------
// Pre-GEMM (R4-proven): C[128x128] = A@B^T, split-3 (NSPLIT=3) or 1-pass.
// ---------------------------------------------------------------------------
template<int NSPLIT, bool SPLITOUT>
__global__ __launch_bounds__(512, 1) void gemm_kernel(
    const u16* __restrict__ ah, const u16* __restrict__ al,
    const u16* __restrict__ bh, const u16* __restrict__ bl,
    const float* __restrict__ bias, u16* __restrict__ ch, u16* __restrict__ cl)
{
  extern __shared__ char smem[];
  constexpr int BUFS = (NSPLIT == 3) ? 65536 : 32768;
  constexpr int AHO = 0, ALO = 16384;
  constexpr int BHO = (NSPLIT == 3) ? 32768 : 16384;
  constexpr int BLO = 49152;
  constexpr int NT = KDIM / 64;

  const int tid = threadIdx.x, w = tid >> 6, lane = tid & 63;
  const int wr = w >> 2, wc = w & 3;
  const int bx = blockIdx.x, by = blockIdx.y;
  const int arow0 = bx * 128, bcol0 = by * 128;

  const int srow = w * 16 + (lane >> 3);
  const int scol = ((lane & 7) ^ (lane >> 3)) * 8;
  const size_t sgA = (size_t)(arow0 + srow) * KDIM + scol;
  const size_t sgB = (size_t)(bcol0 + srow) * KDIM + scol;
  const int ldsw = w * 2048;

  auto stg = [&](const u16* src, size_t sg, int kt, int ldsoff) {
    const u16* sp = src + sg + kt * 64;
    glds16(sp,            smem + ldsoff + ldsw);
    glds16(sp + 8 * KDIM, smem + ldsoff + ldsw + 1024);
  };

  const int fa = (wr * 64 + (lane & 15)) * 128;
  const int fb = (wc * 32 + (lane & 15)) * 128;
  const int kqx0 = (((lane >> 4)    ) ^ (lane & 7)) * 16;
  const int kqx1 = (((lane >> 4) + 4) ^ (lane & 7)) * 16;

  stg(ah, sgA, 0, AHO); stg(bh, sgB, 0, BHO);
  if constexpr (NSPLIT == 3) { stg(al, sgA, 0, ALO); stg(bl, sgB, 0, BLO); }
  else { stg(ah, sgA, 1, AHO + BUFS); stg(bh, sgB, 1, BHO + BUFS); }

  f32x4 acc[4][2];
  #pragma unroll
  for (int m = 0; m < 4; ++m) {
    acc[m][0] = f32x4{0.f, 0.f, 0.f, 0.f};
    acc[m][1] = f32x4{0.f, 0.f, 0.f, 0.f};
  }

  for (int t = 0; t < NT; ++t) {
    const int bo  = (t & 1) * BUFS;
    const int bo2 = ((t + 1) & 1) * BUFS;

    if (NSPLIT == 1 && t == NT - 1) asm volatile("s_waitcnt vmcnt(0)" ::: "memory");
    else                            asm volatile("s_waitcnt vmcnt(4)" ::: "memory");
    __builtin_amdgcn_s_barrier();
    __builtin_amdgcn_sched_barrier(0);

    if (NSPLIT == 3 && t + 1 < NT) {
      stg(ah, sgA, t + 1, AHO + bo2);
      stg(bh, sgB, t + 1, BHO + bo2);
    }

    bf16x8 a0[4][2], b0[2][2];
    #pragma unroll
    for (int m = 0; m < 4; ++m) {
      a0[m][0] = *(const bf16x8*)(smem + AHO + bo + fa + m * 2048 + kqx0);
      a0[m][1] = *(const bf16x8*)(smem + AHO + bo + fa + m * 2048 + kqx1);
    }
    #pragma unroll
    for (int n = 0; n < 2; ++n) {
      b0[n][0] = *(const bf16x8*)(smem + BHO + bo + fb + n * 2048 + kqx0);
      b0[n][1] = *(const bf16x8*)(smem + BHO + bo + fb + n * 2048 + kqx1);
    }
    __builtin_amdgcn_s_setprio(1);
    #pragma unroll
    for (int kq = 0; kq < 2; ++kq)
      #pragma unroll
      for (int m = 0; m < 4; ++m)
        #pragma unroll
        for (int n = 0; n < 2; ++n)
          acc[m][n] = mfma16(a0[m][kq], b0[n][kq], acc[m][n]);
    __builtin_amdgcn_s_setprio(0);
    asm volatile("s_waitcnt lgkmcnt(0)" ::: "memory");

    if constexpr (NSPLIT == 3) {
      if (t + 1 < NT) asm volatile("s_waitcnt vmcnt(4)" ::: "memory");
      else            asm volatile("s_waitcnt vmcnt(0)" ::: "memory");
      __builtin_amdgcn_s_barrier();
      __builtin_amdgcn_sched_barrier(0);

      if (t + 1 < NT) {
        stg(al, sgA, t + 1, ALO + bo2);
        stg(bl, sgB, t + 1, BLO + bo2);
      }
      bf16x8 a1[4][2], b1[2][2];
      #pragma unroll
      for (int m = 0; m < 4; ++m) {
        a1[m][0] = *(const bf16x8*)(smem + ALO + bo + fa + m * 2048 + kqx0);
        a1[m][1] = *(const bf16x8*)(smem + ALO + bo + fa + m * 2048 + kqx1);
      }
      #pragma unroll
      for (int n = 0; n < 2; ++n) {
        b1[n][0] = *(const bf16x8*)(smem + BLO + bo + fb + n * 2048 + kqx0);
        b1[n][1] = *(const bf16x8*)(smem + BLO + bo + fb + n * 2048 + kqx1);
      }
      __builtin_amdgcn_s_setprio(1);
      #pragma unroll
      for (int kq = 0; kq < 2; ++kq)
        #pragma unroll
        for (int m = 0; m < 4; ++m)
          #pragma unroll
          for (int n = 0; n < 2; ++n)
            acc[m][n] = mfma16(a1[m][kq], b0[n][kq], acc[m][n]);
      #pragma unroll
      for (int kq = 0; kq < 2; ++kq)
        #pragma unroll
        for (int m = 0; m < 4; ++m)
          #pragma unroll
          for (int n = 0; n < 2; ++n)
            acc[m][n] = mfma16(a0[m][kq], b1[n][kq], acc[m][n]);
      __builtin_amdgcn_s_setprio(0);
      asm volatile("s_waitcnt lgkmcnt(0)" ::: "memory");
    } else {
      __builtin_amdgcn_s_barrier();
      if (t + 2 < NT) {
        stg(ah, sgA, t + 2, AHO + bo);
        stg(bh, sgB, t + 2, BHO + bo);
      }
    }
  }

  const int l15 = lane & 15, g4 = (lane >> 4) << 2;
  const int colb = bcol0 + wc * 32 + l15;
  const float bi0 = bias[colb], bi1 = bias[colb + 16];
  #pragma unroll
  for (int m = 0; m < 4; ++m) {
    #pragma unroll
    for (int j = 0; j < 4; ++j) {
      const int row = arow0 + wr * 64 + m * 16 + g4 + j;
      float v0 = acc[m][0][j] + bi0, v1 = acc[m][1][j] + bi1;
      u16 h0 = f2bf(v0), h1 = f2bf(v1);
      ch[(size_t)row * KDIM + colb] = h0;
      ch[(size_t)row * KDIM + colb + 16] = h1;
      if constexpr (SPLITOUT) {
        cl[(size_t)row * KDIM + colb] = f2bf(v0 - bf2f(h0));
        cl[(size_t)row * KDIM + colb + 16] = f2bf(v1 - bf2f(h1));
      }
    }
  }
}

// ---------------------------------------------------------------------------
// Scores sweep R11 = R9's counted-vmcnt 4-phase schedule (proven sound) +
// R6's XCD mapping (185MB FETCH measured) + latency-overlapped epilogue.
// 256x256 tile, BK=64, 2x64KB dbuf, 16x16x32 MFMA with the R4/R6/R9 layout
// (128B rows, slot = kq ^ (row&7); 0 conflicts measured).
// Phases per K-tile T (each: work -> barrier -> lgkm(0) -> prio1 -> 16 MFMA
//   -> prio0 -> barrier):
//   p0: read a0-3, b0-1 | p1: read a4-7 | p2: read b2-3; stage A(T+2)
//   p3: stage B(T+2); vmcnt(8)  [newest 8 = T+2's stages -> tile T+1 landed]
// Epilogue (every 16 tiles): chunks of 8 (m,j) iters, 3 sub-phases:
//   A) batch-prefetch adjb words + rowmax (independent loads overlap)
//   B) scores/masks/shfl-reduce; fire atomicMax; issue 8 independent
//      atomicAdds (returns consumed in C -> latencies overlap)
//   C) re-ballot, place, store candidates.
// ---------------------------------------------------------------------------
__global__ __launch_bounds__(512, 2) void scores_kernel(
    const u16* __restrict__ fh, const u16* __restrict__ gh,
    const uint32_t* __restrict__ adjb, uint32_t* __restrict__ cand,
    int* __restrict__ cnts, int* rowmax)
{
  extern __shared__ char smem[];
  constexpr int NT = 64;                 // 4 key-tiles x 16 K-tiles

  const int tid = threadIdx.x, w = tid >> 6, lane = tid & 63;
  const int wr = w >> 2, wc = w & 3;
  const int l15 = lane & 15, g4 = (lane >> 4) << 2;

  // R6 mapping: XCD hosts 4 A-slabs (2MB, L2-fit) x 8 siblings
  const int xcd = blockIdx.x & 7, idx = blockIdx.x >> 3;
  const int bx  = xcd * 4 + (idx & 3);
  const int sub = idx >> 2;              // sibling 0..7 -> key panels {sub+8it}
  const int arow0 = bx * 256;

  // ---- staging: cell=tid -> row=tid>>3, slot=tid&7, content kq=slot^(row&7)
  const int srow = tid >> 3;
  const int skq  = (tid & 7) ^ (srow & 7);
  const int sdw  = w * 1024;

  auto stageA = [&](int T, int half) {
    char* d = smem + (T & 1) * 65536 + half * 16384 + sdw;
    const u16* s = fh + (size_t)(arow0 + half * 128 + srow) * KDIM
                      + (T & 15) * 64 + skq * 8;
    glds16(s, d);
    glds16(s + (size_t)64 * KDIM, d + 8192);
  };
  auto stageB = [&](int T, int half) {
    char* d = smem + (T & 1) * 65536 + 32768 + half * 16384 + sdw;
    const u16* s = gh + (size_t)((sub + 8 * (T >> 4)) * 256 + half * 128 + srow) * KDIM
                      + (T & 15) * 64 + skq * 8;
    glds16(s, d);
    glds16(s + (size_t)64 * KDIM, d + 8192);
  };

  // ---- fragment read offsets (R9-proven)
  const int kxa = ((lane >> 4) ^ (l15 & 7)) * 16;        // kq2 = 0
  const int kxb = (((lane >> 4) + 4) ^ (l15 & 7)) * 16;  // kq2 = 1
  const int abase = wr * 16384 + l15 * 128;
  const int bbase = 32768 + (wc >> 1) * 16384 + ((wc & 1) * 64 + l15) * 128;

  f32x4 acc[8][4];
  #pragma unroll
  for (int m = 0; m < 8; ++m)
    #pragma unroll
    for (int n = 0; n < 4; ++n) acc[m][n] = f32x4{0.f, 0.f, 0.f, 0.f};

  const unsigned long long lmask = (1ull << lane) - 1ull;
  const unsigned long long gm = 0xFFFFull << (lane & 48);

  // ---- prologue: stage tiles 0 and 1 (16 glds), publish tile 0
  stageA(0, 0); stageA(0, 1); stageB(0, 0); stageB(0, 1);
  stageA(1, 0); stageA(1, 1); stageB(1, 0); stageB(1, 1);
  asm volatile("s_waitcnt vmcnt(8)" ::: "memory");
  __builtin_amdgcn_s_barrier();

  bf16x8 a[8][2], b[4][2];

  for (int T = 0; T < NT; ++T) {
    const char* sb = smem + (T & 1) * 65536;

    // ===== p0: read a0-3 + b0-1 | MFMA m0-3 x n0-1 =====
    #pragma unroll
    for (int m = 0; m < 4; ++m) {
      a[m][0] = *(const bf16x8*)(sb + abase + m * 2048 + kxa);
      a[m][1] = *(const bf16x8*)(sb + abase + m * 2048 + kxb);
    }
    #pragma unroll
    for (int n = 0; n < 2; ++n) {
      b[n][0] = *(const bf16x8*)(sb + bbase + n * 2048 + kxa);
      b[n][1] = *(const bf16x8*)(sb + bbase + n * 2048 + kxb);
    }
    __builtin_amdgcn_sched_barrier(0);
    __builtin_amdgcn_s_barrier();
    asm volatile("s_waitcnt lgkmcnt(0)" ::: "memory");
    __builtin_amdgcn_s_setprio(1);
    #pragma unroll
    for (int kq = 0; kq < 2; ++kq)
      #pragma unroll
      for (int m = 0; m < 4; ++m)
        #pragma unroll
        for (int n = 0; n < 2; ++n)
          acc[m][n] = mfma16(a[m][kq], b[n][kq], acc[m][n]);
    __builtin_amdgcn_s_setprio(0);
    __builtin_amdgcn_sched_barrier(0);
    __builtin_amdgcn_s_barrier();

    // ===== p1: read a4-7 | MFMA m4-7 x n0-1 =====
    #pragma unroll
    for (int m = 4; m < 8; ++m) {
      a[m][0] = *(const bf16x8*)(sb + abase + m * 2048 + kxa);
      a[m][1] = *(const bf16x8*)(sb + abase + m * 2048 + kxb);
    }
    __builtin_amdgcn_sched_barrier(0);
    __builtin_amdgcn_s_barrier();
    asm volatile("s_waitcnt lgkmcnt(0)" ::: "memory");
    __builtin_amdgcn_s_setprio(1);
    #pragma unroll
    for (int kq = 0; kq < 2; ++kq)
      #pragma unroll
      for (int m = 4; m < 8; ++m)
        #pragma unroll
        for (int n = 0; n < 2; ++n)
          acc[m][n] = mfma16(a[m][kq], b[n][kq], acc[m][n]);
    __builtin_amdgcn_s_setprio(0);
    __builtin_amdgcn_sched_barrier(0);
    __builtin_amdgcn_s_barrier();

    // ===== p2: read b2-3; stage A(T+2) | MFMA m0-3 x n2-3 =====
    #pragma unroll
    for (int n = 2; n < 4; ++n) {
      b[n][0] = *(const bf16x8*)(sb + bbase + n * 2048 + kxa);
      b[n][1] = *(const bf16x8*)(sb + bbase + n * 2048 + kxb);
    }
    if (T + 2 < NT) { stageA(T + 2, 0); stageA(T + 2, 1); }
    __builtin_amdgcn_sched_barrier(0);
    __builtin_amdgcn_s_barrier();
    asm volatile("s_waitcnt lgkmcnt(0)" ::: "memory");
    __builtin_amdgcn_s_setprio(1);
    #pragma unroll
    for (int kq = 0; kq < 2; ++kq)
      #pragma unroll
      for (int m = 0; m < 4; ++m)
        #pragma unroll
        for (int n = 2; n < 4; ++n)
          acc[m][n] = mfma16(a[m][kq], b[n][kq], acc[m][n]);
    __builtin_amdgcn_s_setprio(0);
    __builtin_amdgcn_sched_barrier(0);
    __builtin_amdgcn_s_barrier();

    // ===== p3: stage B(T+2); counted vmcnt | MFMA m4-7 x n2-3 =====
    if (T + 2 < NT) {
      stageB(T + 2, 0); stageB(T + 2, 1);
      asm volatile("s_waitcnt vmcnt(8)" ::: "memory");
    } else {
      asm volatile("s_waitcnt vmcnt(0)" ::: "memory");
    }
    __builtin_amdgcn_sched_barrier(0);
    __builtin_amdgcn_s_barrier();
    asm volatile("s_waitcnt lgkmcnt(0)" ::: "memory");
    __builtin_amdgcn_s_setprio(1);
    #pragma unroll
    for (int kq = 0; kq < 2; ++kq)
      #pragma unroll
      for (int m = 4; m < 8; ++m)
        #pragma unroll
        for (int n = 2; n < 4; ++n)
          acc[m][n] = mfma16(a[m][kq], b[n][kq], acc[m][n]);
    __builtin_amdgcn_s_setprio(0);
    __builtin_amdgcn_sched_barrier(0);
    __builtin_amdgcn_s_barrier();

    // ===== key-tile epilogue (every 16 K-tiles), latency-overlapped =====
    if ((T & 15) == 15) {
      const int it = T >> 4;
      const int bcol0 = (sub + 8 * it) * 256;
      const int keyb = bcol0 + wc * 64 + l15;
      #pragma unroll
      for (int mc = 0; mc < 4; ++mc) {
        // -- phase A: batch-prefetch adjacency + rowmax (overlapped loads)
        uint32_t A0[2][4], A1[2][4]; float RX[2][4]; int ROW[2][4];
        #pragma unroll
        for (int mm = 0; mm < 2; ++mm)
          #pragma unroll
          for (int j = 0; j < 4; ++j) {
            const int m = mc * 2 + mm;
            const int row = arow0 + wr * 128 + m * 16 + g4 + j;
            ROW[mm][j] = row;
            const uint32_t* ap = adjb + (size_t)row * (NROWS / 32) + (bcol0 >> 5) + wc * 2;
            A0[mm][j] = ap[0];
            A1[mm][j] = ap[1];
            RX[mm][j] = __int_as_float(rowmax[row]);   // stale-tolerant
          }
        // -- phase B: scores/masks/reduce; fire atomicMax; issue atomicAdds
        float SV[2][4][4]; float TH[2][4]; int BS[2][4];
        #pragma unroll
        for (int mm = 0; mm < 2; ++mm)
          #pragma unroll
          for (int j = 0; j < 4; ++j) {
            const int m = mc * 2 + mm;
            float rm = NEGBIG;
            #pragma unroll
            for (int n = 0; n < 4; ++n) {
              float v = fmaxf(acc[m][n][j], 0.f);
              uint32_t bit = ((n < 2 ? A0[mm][j] : A1[mm][j]) >> ((n & 1) * 16 + l15)) & 1u;
              float s = bit ? v : NEGBIG;
              SV[mm][j][n] = s;
              rm = fmaxf(rm, s);
            }
            rm = fmaxf(rm, __shfl_xor(rm, 1));
            rm = fmaxf(rm, __shfl_xor(rm, 2));
            rm = fmaxf(rm, __shfl_xor(rm, 4));
            rm = fmaxf(rm, __shfl_xor(rm, 8));
            const float mr = fmaxf(rm, RX[mm][j]);
            if (l15 == 0 && rm > RX[mm][j])
              atomicMax(rowmax + ROW[mm][j], __float_as_int(rm));
            TH[mm][j] = mr - EMIT_THR;
            int tot = 0;
            #pragma unroll
            for (int n = 0; n < 4; ++n)
              tot += __popcll(__ballot(SV[mm][j][n] > TH[mm][j]) & gm);
            BS[mm][j] = 0;
            if (l15 == 0 && tot > 0)
              BS[mm][j] = atomicAdd(cnts + ROW[mm][j], tot);
          }
        // -- phase C: re-ballot, place, store (atomic returns now landed)
        #pragma unroll
        for (int mm = 0; mm < 2; ++mm)
          #pragma unroll
          for (int j = 0; j < 4; ++j) {
            int base = __shfl(BS[mm][j], lane & 48);
            int pref = 0;
            #pragma unroll
            for (int n = 0; n < 4; ++n) {
              unsigned long long mk = __ballot(SV[mm][j][n] > TH[mm][j]);
              const int p = base + pref + __popcll(mk & gm & lmask);
              if ((SV[mm][j][n] > TH[mm][j]) && p < CAP)
                cand[(size_t)ROW[mm][j] * CAP + p] =
                    ((uint32_t)f2bf(SV[mm][j][n]) << 16) | (uint32_t)(keyb + n * 16);
              pref += __popcll(mk & gm);
            }
          }
      }
      #pragma unroll
      for (int m = 0; m < 8; ++m)
        #pragma unroll
        for (int n = 0; n < 4; ++n) acc[m][n] = f32x4{0.f, 0.f, 0.f, 0.f};
    }
  }
}

// ---------------------------------------------------------------------------
// adj (int32 0/1, 268 MB) -> bitmask (8 MB). BW-bound single pass.
// ---------------------------------------------------------------------------
__global__ __launch_bounds__(256) void adjpack_kernel(
    const int* __restrict__ adj, uint32_t* __restrict__ adjb)
{
  size_t w = (size_t)blockIdx.x * 256 + threadIdx.x;
  const int* src = adj + (w << 5);
  uint32_t m = 0;
  #pragma unroll
  for (int j = 0; j < 8; ++j) {
    i32x4 v = *(const i32x4*)(src + j * 4);
    m |= (v[0] > 0 ? 1u : 0u) << (j * 4)
       | (v[1] > 0 ? 1u : 0u) << (j * 4 + 1)
       | (v[2] > 0 ? 1u : 0u) << (j * 4 + 2)
       | (v[3] > 0 ? 1u : 0u) << (j * 4 + 3);
  }
  adjb[w] = m;
}

// ---------------------------------------------------------------------------
// Finalize: survivors (within SURV_THR of approx max) rescored exactly in
// fp32 from (fh+fl, gh+gl); tail stays approx in the denominator only.
// ---------------------------------------------------------------------------
__global__ __launch_bounds__(256) void finalize_kernel(
    const uint32_t* __restrict__ cand, const int* __restrict__ cnts,
    const u16* __restrict__ fh, const u16* __restrict__ fl,
    const u16* __restrict__ gh, const u16* __restrict__ gl,
    const u16* __restrict__ vh, float* __restrict__ out)
{
  const int row = blockIdx.x, tid = threadIdx.x, wv = tid >> 6, lane = tid & 63;
  __shared__ float sS[CAP];
  __shared__ int sK[CAP];
  __shared__ float sF[KDIM];
  __shared__ float sEx[MAXS];
  __shared__ int sKs[MAXS];
  __shared__ float red[4];
  __shared__ int nsig;
  int cnt = cnts[row]; cnt = cnt < CAP ? cnt : CAP;
  const int col = tid * 4;
  if (cnt <= 0) {
    f32x4 z = {0.f, 0.f, 0.f, 0.f};
    *(f32x4*)(out + (size_t)row * KDIM + col) = z;
    return;
  }
  if (tid == 0) nsig = 0;
  {
    us4 h = *(const us4*)(fh + (size_t)row * KDIM + col);
    us4 l = *(const us4*)(fl + (size_t)row * KDIM + col);
    #pragma unroll
    for (int j = 0; j < 4; ++j) sF[col + j] = bf2f(h[j]) + bf2f(l[j]);
  }
  for (int i = tid; i < cnt; i += 256) {
    uint32_t pk = cand[(size_t)row * CAP + i];
    sS[i] = bf2f((u16)(pk >> 16));
    sK[i] = (int)(pk & 0xFFFFu);
  }
  __syncthreads();
  float lm = NEGBIG;
  for (int i = tid; i < cnt; i += 256) lm = fmaxf(lm, sS[i]);
  #pragma unroll
  for (int d = 1; d < 64; d <<= 1) lm = fmaxf(lm, __shfl_xor(lm, d));
  if ((tid & 63) == 0) red[tid >> 6] = lm;
  __syncthreads();
  const float am = fmaxf(fmaxf(red[0], red[1]), fmaxf(red[2], red[3]));
  __syncthreads();
  for (int i = tid; i < cnt; i += 256) {
    if (sS[i] > am - SURV_THR) {
      int p = atomicAdd(&nsig, 1);
      if (p < MAXS) { sKs[p] = sK[i]; sS[i] = NEGBIG; }
    }
  }
  __syncthreads();
  const int ns = nsig < MAXS ? nsig : MAXS;
  for (int si = wv; si < ns; si += 4) {
    const int key = sKs[si];
    const u16* grh = gh + (size_t)key * KDIM + lane * 16;
    const u16* grl = gl + (size_t)key * KDIM + lane * 16;
    float d = 0.f;
    #pragma unroll
    for (int u = 0; u < 4; ++u) {
      us4 h = *(const us4*)(grh + u * 4);
      us4 l = *(const us4*)(grl + u * 4);
      #pragma unroll
      for (int j = 0; j < 4; ++j)
        d += (bf2f(h[j]) + bf2f(l[j])) * sF[lane * 16 + u * 4 + j];
    }
    #pragma unroll
    for (int dd = 1; dd < 64; dd <<= 1) d += __shfl_xor(d, dd);
    if (lane == 0) sEx[si] = fmaxf(d, 0.f);
  }
  __syncthreads();
  float em = NEGBIG;
  for (int i = tid; i < ns; i += 256) em = fmaxf(em, sEx[i]);
  #pragma unroll
  for (int d = 1; d < 64; d <<= 1) em = fmaxf(em, __shfl_xor(em, d));
  if ((tid & 63) == 0) red[tid >> 6] = em;
  __syncthreads();
  const float m = fmaxf(fmaxf(red[0], red[1]), fmaxf(red[2], red[3]));
  __syncthreads();
  float ls = 0.f;
  for (int i = tid; i < cnt; i += 256) {
    float s = sS[i];
    if (s > NEGBIG * 0.5f) ls += __expf(s - m);
  }
  for (int i = tid; i < ns; i += 256) ls += __expf(sEx[i] - m);
  #pragma unroll
  for (int d = 1; d < 64; d <<= 1) ls += __shfl_xor(ls, d);
  if ((tid & 63) == 0) red[tid >> 6] = ls;
  __syncthreads();
  const float inv = 1.f / (red[0] + red[1] + red[2] + red[3]);
  float a0 = 0.f, a1 = 0.f, a2 = 0.f, a3 = 0.f;
  const u16* vbase = vh + col;
  for (int i = 0; i < ns; ++i) {
    const float wt = __expf(sEx[i] - m) * inv;
    us4 vv = *(const us4*)(vbase + (size_t)sKs[i] * KDIM);
    a0 += wt * bf2f(vv[0]); a1 += wt * bf2f(vv[1]);
    a2 += wt * bf2f(vv[2]); a3 += wt * bf2f(vv[3]);
  }
  f32x4 o = {a0, a1, a2, a3};
  *(f32x4*)(out + (size_t)row * KDIM + col) = o;
}

// ---------------------------------------------------------------------------
// Transpose + hi/lo split of a [K][N] fp32 weight into [N][K] bf16 pair.
// ---------------------------------------------------------------------------
__global__ __launch_bounds__(256) void wsplit_kernel(
    const float* __restrict__ W, u16* __restrict__ th, u16* __restrict__ tl)
{
  __shared__ float tile[32][33];
  const int bx = blockIdx.x, by = blockIdx.y;
  const int tx = threadIdx.x & 31, ty = threadIdx.x >> 5;
  #pragma unroll
  for (int i = 0; i < 4; ++i) {
    int ky = ty + i * 8;
    tile[ky][tx] = W[(size_t)(by * 32 + ky) * KDIM + bx * 32 + tx];
  }
  __syncthreads();
  #pragma unroll
  for (int i = 0; i < 4; ++i) {
    int ny = ty + i * 8;
    float v = tile[tx][ny];
    u16 h = f2bf(v);
    th[(size_t)(bx * 32 + ny) * KDIM + by * 32 + tx] = h;
    tl[(size_t)(bx * 32 + ny) * KDIM + by * 32 + tx] = f2bf(v - bf2f(h));
  }
}

__global__ __launch_bounds__(256) void xsplit_kernel(
    const float* __restrict__ x, u16* __restrict__ xh, u16* __restrict__ xl)
{
  size_t i = ((size_t)blockIdx.x * 256 + threadIdx.x) * 4;
  f32x4 v = *(const f32x4*)(x + i);
  us4 h, l;
  #pragma unroll
  for (int j = 0; j < 4; ++j) {
    h[j] = f2bf(v[j]);
    l[j] = f2bf(v[j] - bf2f(h[j]));
  }
  *(us4*)(xh + i) = h;
  *(us4*)(xl + i) = l;
}

__global__ void ws_report(float* out, size_t n, float v) {
  for (size_t i = (size_t)blockIdx.x * blockDim.x + threadIdx.x; i < n;
       i += (size_t)gridDim.x * blockDim.x) out[i] = v;
}

extern "C" void kernel_launch(void* const* d_in, const int* in_sizes, int n_in,
                              void* d_out, int out_size, void* d_ws, size_t ws_size,
                              hipStream_t stream) {
  (void)in_sizes; (void)n_in;
  const float* x   = (const float*)d_in[0];
  const int*   adj = (const int*)d_in[1];
  const float* Wf  = (const float*)d_in[2];
  const float* bf_ = (const float*)d_in[3];
  const float* Wg  = (const float*)d_in[4];
  const float* bg_ = (const float*)d_in[5];
  const float* W   = (const float*)d_in[6];
  const float* bW_ = (const float*)d_in[7];

  char* p = (char*)d_ws;
  const size_t ND2 = (size_t)NROWS * KDIM * 2;
  const size_t W2  = (size_t)KDIM * KDIM * 2;
  u16* xh = (u16*)p;  p += ND2;
  u16* xl = (u16*)p;  p += ND2;
  u16* fh = (u16*)p;  p += ND2;
  u16* fl = (u16*)p;  p += ND2;
  u16* gh = (u16*)p;  p += ND2;
  u16* gl = (u16*)p;  p += ND2;
  u16* vh = (u16*)p;  p += ND2;
  u16* wfh = (u16*)p; p += W2;
  u16* wfl = (u16*)p; p += W2;
  u16* wgh = (u16*)p; p += W2;
  u16* wgl = (u16*)p; p += W2;
  u16* wh  = (u16*)p; p += W2;
  u16* wl  = (u16*)p; p += W2;
  uint32_t* cand = (uint32_t*)p; p += (size_t)NROWS * CAP * 4;
  int* cnts   = (int*)p; p += (size_t)NROWS * 4;
  int* rowmax = (int*)p; p += (size_t)NROWS * 4;
  const size_t need = (size_t)(p - (char*)d_ws);
  if (ws_size < need) {
    ws_report<<<256, 256, 0, stream>>>((float*)d_out, (size_t)out_size, (float)ws_size);
    return;
  }
  uint32_t* adjb = (uint32_t*)xl;   // aliases xl after pre-GEMMs are done

  auto kf = gemm_kernel<3, true>;
  auto kv = gemm_kernel<1, false>;
  hipFuncSetAttribute((const void*)kf, hipFuncAttributeMaxDynamicSharedMemorySize, 131072);
  hipFuncSetAttribute((const void*)kv, hipFuncAttributeMaxDynamicSharedMemorySize, 65536);
  hipFuncSetAttribute((const void*)scores_kernel, hipFuncAttributeMaxDynamicSharedMemorySize, 131072);

  hipMemsetAsync(cnts, 0, (size_t)NROWS * 8, stream);   // cnts + rowmax (0 == 0.0f)
  wsplit_kernel<<<dim3(32, 32), 256, 0, stream>>>(Wf, wfh, wfl);
  wsplit_kernel<<<dim3(32, 32), 256, 0, stream>>>(Wg, wgh, wgl);
  wsplit_kernel<<<dim3(32, 32), 256, 0, stream>>>(W, wh, wl);
  xsplit_kernel<<<(NROWS * KDIM) / (256 * 4), 256, 0, stream>>>(x, xh, xl);

  // f = x@Wf + bf, g = x@Wg + bg (split-3, hi+lo out), v = x@W + bW (1 pass)
  kf<<<dim3(64, 8), 512, 131072, stream>>>(xh, xl, wfh, wfl, bf_, fh, fl);
  kf<<<dim3(64, 8), 512, 131072, stream>>>(xh, xl, wgh, wgl, bg_, gh, gl);
  kv<<<dim3(64, 8), 512, 65536, stream>>>(xh, xl, wh, wl, bW_, vh, nullptr);
  adjpack_kernel<<<(NROWS * (NROWS / 32)) / 256, 256, 0, stream>>>(adj, adjb);
  // counted-vmcnt 4-phase 256x256 scores sweep + bounded candidate emission
  scores_kernel<<<dim3(256), 512, 131072, stream>>>(fh, gh, adjb, cand, cnts, rowmax);
  // exact rescoring of survivors + softmax + v gather
  finalize_kernel<<<NROWS, 256, 0, stream>>>(cand, cnts, fh, fl, gh, gl, vh,
                                             (float*)d_out);
}

// Round 12
// 558.347 us; speedup vs baseline: 1.2237x; 1.0132x over previous
//
#include <hip/hip_runtime.h>
#include <stdint.h>

#define NROWS 8192
#define KDIM  1024
#define CAP   512
#define NEGBIG (-9.0e15f)
#define EMIT_THR 16.0f
#define SURV_THR 13.5f
#define MAXS  128

typedef __attribute__((ext_vector_type(8))) __bf16 bf16x8;
typedef __attribute__((ext_vector_type(4))) float f32x4;
typedef __attribute__((ext_vector_type(4))) unsigned short us4;
typedef __attribute__((ext_vector_type(4))) int i32x4;
typedef unsigned short u16;

__device__ __forceinline__ u16 f2bf(float f) {
  unsigned u = __float_as_uint(f);
  u += 0x7fffu + ((u >> 16) & 1u);
  return (u16)(u >> 16);
}
__device__ __forceinline__ float bf2f(u16 h) {
  return __uint_as_float(((unsigned)h) << 16);
}

__device__ __forceinline__ void glds16(const void* g, const char* lds) {
  __builtin_amdgcn_global_load_lds(
      (const __attribute__((address_space(1))) unsigned int*)(uintptr_t)g,
      (__attribute__((address_space(3))) unsigned int*)(uintptr_t)lds, 16, 0, 0);
}

__device__ __forceinline__ f32x4 mfma16(bf16x8 a, bf16x8 b, f32x4 c) {
  return __builtin_amdgcn_mfma_f32_16x16x32_bf16(a, b, c, 0, 0, 0);
}

// ---------------------------------------------------------------------------
// Pre-GEMM (R4-proven): C[128x128] = A@B^T, split-3 (NSPLIT=3) or 1-pass.
// ---------------------------------------------------------------------------
template<int NSPLIT, bool SPLITOUT>
__global__ __launch_bounds__(512, 1) void gemm_kernel(
    const u16* __restrict__ ah, const u16* __restrict__ al,
    const u16* __restrict__ bh, const u16* __restrict__ bl,
    const float* __restrict__ bias, u16* __restrict__ ch, u16* __restrict__ cl)
{
  extern __shared__ char smem[];
  constexpr int BUFS = (NSPLIT == 3) ? 65536 : 32768;
  constexpr int AHO = 0, ALO = 16384;
  constexpr int BHO = (NSPLIT == 3) ? 32768 : 16384;
  constexpr int BLO = 49152;
  constexpr int NT = KDIM / 64;

  const int tid = threadIdx.x, w = tid >> 6, lane = tid & 63;
  const int wr = w >> 2, wc = w & 3;
  const int bx = blockIdx.x, by = blockIdx.y;
  const int arow0 = bx * 128, bcol0 = by * 128;

  const int srow = w * 16 + (lane >> 3);
  const int scol = ((lane & 7) ^ (lane >> 3)) * 8;
  const size_t sgA = (size_t)(arow0 + srow) * KDIM + scol;
  const size_t sgB = (size_t)(bcol0 + srow) * KDIM + scol;
  const int ldsw = w * 2048;

  auto stg = [&](const u16* src, size_t sg, int kt, int ldsoff) {
    const u16* sp = src + sg + kt * 64;
    glds16(sp,            smem + ldsoff + ldsw);
    glds16(sp + 8 * KDIM, smem + ldsoff + ldsw + 1024);
  };

  const int fa = (wr * 64 + (lane & 15)) * 128;
  const int fb = (wc * 32 + (lane & 15)) * 128;
  const int kqx0 = (((lane >> 4)    ) ^ (lane & 7)) * 16;
  const int kqx1 = (((lane >> 4) + 4) ^ (lane & 7)) * 16;

  stg(ah, sgA, 0, AHO); stg(bh, sgB, 0, BHO);
  if constexpr (NSPLIT == 3) { stg(al, sgA, 0, ALO); stg(bl, sgB, 0, BLO); }
  else { stg(ah, sgA, 1, AHO + BUFS); stg(bh, sgB, 1, BHO + BUFS); }

  f32x4 acc[4][2];
  #pragma unroll
  for (int m = 0; m < 4; ++m) {
    acc[m][0] = f32x4{0.f, 0.f, 0.f, 0.f};
    acc[m][1] = f32x4{0.f, 0.f, 0.f, 0.f};
  }

  for (int t = 0; t < NT; ++t) {
    const int bo  = (t & 1) * BUFS;
    const int bo2 = ((t + 1) & 1) * BUFS;

    if (NSPLIT == 1 && t == NT - 1) asm volatile("s_waitcnt vmcnt(0)" ::: "memory");
    else                            asm volatile("s_waitcnt vmcnt(4)" ::: "memory");
    __builtin_amdgcn_s_barrier();
    __builtin_amdgcn_sched_barrier(0);

    if (NSPLIT == 3 && t + 1 < NT) {
      stg(ah, sgA, t + 1, AHO + bo2);
      stg(bh, sgB, t + 1, BHO + bo2);
    }

    bf16x8 a0[4][2], b0[2][2];
    #pragma unroll
    for (int m = 0; m < 4; ++m) {
      a0[m][0] = *(const bf16x8*)(smem + AHO + bo + fa + m * 2048 + kqx0);
      a0[m][1] = *(const bf16x8*)(smem + AHO + bo + fa + m * 2048 + kqx1);
    }
    #pragma unroll
    for (int n = 0; n < 2; ++n) {
      b0[n][0] = *(const bf16x8*)(smem + BHO + bo + fb + n * 2048 + kqx0);
      b0[n][1] = *(const bf16x8*)(smem + BHO + bo + fb + n * 2048 + kqx1);
    }
    __builtin_amdgcn_s_setprio(1);
    #pragma unroll
    for (int kq = 0; kq < 2; ++kq)
      #pragma unroll
      for (int m = 0; m < 4; ++m)
        #pragma unroll
        for (int n = 0; n < 2; ++n)
          acc[m][n] = mfma16(a0[m][kq], b0[n][kq], acc[m][n]);
    __builtin_amdgcn_s_setprio(0);
    asm volatile("s_waitcnt lgkmcnt(0)" ::: "memory");

    if constexpr (NSPLIT == 3) {
      if (t + 1 < NT) asm volatile("s_waitcnt vmcnt(4)" ::: "memory");
      else            asm volatile("s_waitcnt vmcnt(0)" ::: "memory");
      __builtin_amdgcn_s_barrier();
      __builtin_amdgcn_sched_barrier(0);

      if (t + 1 < NT) {
        stg(al, sgA, t + 1, ALO + bo2);
        stg(bl, sgB, t + 1, BLO + bo2);
      }
      bf16x8 a1[4][2], b1[2][2];
      #pragma unroll
      for (int m = 0; m < 4; ++m) {
        a1[m][0] = *(const bf16x8*)(smem + ALO + bo + fa + m * 2048 + kqx0);
        a1[m][1] = *(const bf16x8*)(smem + ALO + bo + fa + m * 2048 + kqx1);
      }
      #pragma unroll
      for (int n = 0; n < 2; ++n) {
        b1[n][0] = *(const bf16x8*)(smem + BLO + bo + fb + n * 2048 + kqx0);
        b1[n][1] = *(const bf16x8*)(smem + BLO + bo + fb + n * 2048 + kqx1);
      }
      __builtin_amdgcn_s_setprio(1);
      #pragma unroll
      for (int kq = 0; kq < 2; ++kq)
        #pragma unroll
        for (int m = 0; m < 4; ++m)
          #pragma unroll
          for (int n = 0; n < 2; ++n)
            acc[m][n] = mfma16(a1[m][kq], b0[n][kq], acc[m][n]);
      #pragma unroll
      for (int kq = 0; kq < 2; ++kq)
        #pragma unroll
        for (int m = 0; m < 4; ++m)
          #pragma unroll
          for (int n = 0; n < 2; ++n)
            acc[m][n] = mfma16(a0[m][kq], b1[n][kq], acc[m][n]);
      __builtin_amdgcn_s_setprio(0);
      asm volatile("s_waitcnt lgkmcnt(0)" ::: "memory");
    } else {
      __builtin_amdgcn_s_barrier();
      if (t + 2 < NT) {
        stg(ah, sgA, t + 2, AHO + bo);
        stg(bh, sgB, t + 2, BHO + bo);
      }
    }
  }

  const int l15 = lane & 15, g4 = (lane >> 4) << 2;
  const int colb = bcol0 + wc * 32 + l15;
  const float bi0 = bias[colb], bi1 = bias[colb + 16];
  #pragma unroll
  for (int m = 0; m < 4; ++m) {
    #pragma unroll
    for (int j = 0; j < 4; ++j) {
      const int row = arow0 + wr * 64 + m * 16 + g4 + j;
      float v0 = acc[m][0][j] + bi0, v1 = acc[m][1][j] + bi1;
      u16 h0 = f2bf(v0), h1 = f2bf(v1);
      ch[(size_t)row * KDIM + colb] = h0;
      ch[(size_t)row * KDIM + colb + 16] = h1;
      if constexpr (SPLITOUT) {
        cl[(size_t)row * KDIM + colb] = f2bf(v0 - bf2f(h0));
        cl[(size_t)row * KDIM + colb + 16] = f2bf(v1 - bf2f(h1));
      }
    }
  }
}

// ---------------------------------------------------------------------------
// Scores sweep R12 = R11 with the schedule UN-PINNED: no sched_barrier(0),
// no blanket lgkmcnt(0) drains (m141: order-pinning costs ~1.7x; the
// compiler inserts fine-grained lgkm waits itself, m97). Kept invariants:
//   - counted vmcnt(8) + barrier at p3 (RAW publish of tile T+1's stages;
//     compiler cannot infer glds completion)
//   - lgkmcnt(0) at end-of-p1 / end-of-p2 only (WAR: A-region reads drained
//     before p2's stageA(T+2) lands; B-region before p3's stageB. Free --
//     those reads were already consumed by in-phase MFMAs.)
//   - 2 barriers per phase (m201 shape).
// Geometry identical to R11 (256x256 tile, BK=64, 2x64KB dbuf, 0-conflict
// layout, R6 XCD mapping, overlapped epilogue).
// ---------------------------------------------------------------------------
__global__ __launch_bounds__(512, 2) void scores_kernel(
    const u16* __restrict__ fh, const u16* __restrict__ gh,
    const uint32_t* __restrict__ adjb, uint32_t* __restrict__ cand,
    int* __restrict__ cnts, int* rowmax)
{
  extern __shared__ char smem[];
  constexpr int NT = 64;                 // 4 key-tiles x 16 K-tiles

  const int tid = threadIdx.x, w = tid >> 6, lane = tid & 63;
  const int wr = w >> 2, wc = w & 3;
  const int l15 = lane & 15, g4 = (lane >> 4) << 2;

  // R6 mapping: XCD hosts 4 A-slabs (2MB, L2-fit) x 8 siblings
  const int xcd = blockIdx.x & 7, idx = blockIdx.x >> 3;
  const int bx  = xcd * 4 + (idx & 3);
  const int sub = idx >> 2;              // sibling 0..7 -> key panels {sub+8it}
  const int arow0 = bx * 256;

  // ---- staging: cell=tid -> row=tid>>3, slot=tid&7, content kq=slot^(row&7)
  const int srow = tid >> 3;
  const int skq  = (tid & 7) ^ (srow & 7);
  const int sdw  = w * 1024;

  auto stageA = [&](int T, int half) {
    char* d = smem + (T & 1) * 65536 + half * 16384 + sdw;
    const u16* s = fh + (size_t)(arow0 + half * 128 + srow) * KDIM
                      + (T & 15) * 64 + skq * 8;
    glds16(s, d);
    glds16(s + (size_t)64 * KDIM, d + 8192);
  };
  auto stageB = [&](int T, int half) {
    char* d = smem + (T & 1) * 65536 + 32768 + half * 16384 + sdw;
    const u16* s = gh + (size_t)((sub + 8 * (T >> 4)) * 256 + half * 128 + srow) * KDIM
                      + (T & 15) * 64 + skq * 8;
    glds16(s, d);
    glds16(s + (size_t)64 * KDIM, d + 8192);
  };

  // ---- fragment read offsets (R9-proven, 0 conflicts)
  const int kxa = ((lane >> 4) ^ (l15 & 7)) * 16;        // kq2 = 0
  const int kxb = (((lane >> 4) + 4) ^ (l15 & 7)) * 16;  // kq2 = 1
  const int abase = wr * 16384 + l15 * 128;
  const int bbase = 32768 + (wc >> 1) * 16384 + ((wc & 1) * 64 + l15) * 128;

  f32x4 acc[8][4];
  #pragma unroll
  for (int m = 0; m < 8; ++m)
    #pragma unroll
    for (int n = 0; n < 4; ++n) acc[m][n] = f32x4{0.f, 0.f, 0.f, 0.f};

  const unsigned long long lmask = (1ull << lane) - 1ull;
  const unsigned long long gm = 0xFFFFull << (lane & 48);

  // ---- prologue: stage tiles 0 and 1 (16 glds), publish tile 0
  stageA(0, 0); stageA(0, 1); stageB(0, 0); stageB(0, 1);
  stageA(1, 0); stageA(1, 1); stageB(1, 0); stageB(1, 1);
  asm volatile("s_waitcnt vmcnt(8)" ::: "memory");
  __builtin_amdgcn_s_barrier();

  bf16x8 a[8][2], b[4][2];

  for (int T = 0; T < NT; ++T) {
    const char* sb = smem + (T & 1) * 65536;

    // ===== p0: read a0-3 + b0-1 | MFMA m0-3 x n0-1 =====
    #pragma unroll
    for (int m = 0; m < 4; ++m) {
      a[m][0] = *(const bf16x8*)(sb + abase + m * 2048 + kxa);
      a[m][1] = *(const bf16x8*)(sb + abase + m * 2048 + kxb);
    }
    #pragma unroll
    for (int n = 0; n < 2; ++n) {
      b[n][0] = *(const bf16x8*)(sb + bbase + n * 2048 + kxa);
      b[n][1] = *(const bf16x8*)(sb + bbase + n * 2048 + kxb);
    }
    __builtin_amdgcn_s_barrier();
    __builtin_amdgcn_s_setprio(1);
    #pragma unroll
    for (int kq = 0; kq < 2; ++kq)
      #pragma unroll
      for (int m = 0; m < 4; ++m)
        #pragma unroll
        for (int n = 0; n < 2; ++n)
          acc[m][n] = mfma16(a[m][kq], b[n][kq], acc[m][n]);
    __builtin_amdgcn_s_setprio(0);
    __builtin_amdgcn_s_barrier();

    // ===== p1: read a4-7 | MFMA m4-7 x n0-1 =====
    #pragma unroll
    for (int m = 4; m < 8; ++m) {
      a[m][0] = *(const bf16x8*)(sb + abase + m * 2048 + kxa);
      a[m][1] = *(const bf16x8*)(sb + abase + m * 2048 + kxb);
    }
    __builtin_amdgcn_s_barrier();
    __builtin_amdgcn_s_setprio(1);
    #pragma unroll
    for (int kq = 0; kq < 2; ++kq)
      #pragma unroll
      for (int m = 4; m < 8; ++m)
        #pragma unroll
        for (int n = 0; n < 2; ++n)
          acc[m][n] = mfma16(a[m][kq], b[n][kq], acc[m][n]);
    __builtin_amdgcn_s_setprio(0);
    // WAR: all A-region reads (a0-7) complete before p2's stageA(T+2) lands.
    // Free: a4-7 already consumed by this phase's MFMAs.
    asm volatile("s_waitcnt lgkmcnt(0)" ::: "memory");
    __builtin_amdgcn_s_barrier();

    // ===== p2: read b2-3; stage A(T+2) | MFMA m0-3 x n2-3 =====
    #pragma unroll
    for (int n = 2; n < 4; ++n) {
      b[n][0] = *(const bf16x8*)(sb + bbase + n * 2048 + kxa);
      b[n][1] = *(const bf16x8*)(sb + bbase + n * 2048 + kxb);
    }
    if (T + 2 < NT) { stageA(T + 2, 0); stageA(T + 2, 1); }
    __builtin_amdgcn_s_barrier();
    __builtin_amdgcn_s_setprio(1);
    #pragma unroll
    for (int kq = 0; kq < 2; ++kq)
      #pragma unroll
      for (int m = 0; m < 4; ++m)
        #pragma unroll
        for (int n = 2; n < 4; ++n)
          acc[m][n] = mfma16(a[m][kq], b[n][kq], acc[m][n]);
    __builtin_amdgcn_s_setprio(0);
    // WAR: all B-region reads (b0-3) complete before p3's stageB(T+2) lands.
    asm volatile("s_waitcnt lgkmcnt(0)" ::: "memory");
    __builtin_amdgcn_s_barrier();

    // ===== p3: stage B(T+2); counted vmcnt | MFMA m4-7 x n2-3 =====
    if (T + 2 < NT) {
      stageB(T + 2, 0); stageB(T + 2, 1);
      asm volatile("s_waitcnt vmcnt(8)" ::: "memory");
    } else {
      asm volatile("s_waitcnt vmcnt(0)" ::: "memory");
    }
    __builtin_amdgcn_s_barrier();
    __builtin_amdgcn_s_setprio(1);
    #pragma unroll
    for (int kq = 0; kq < 2; ++kq)
      #pragma unroll
      for (int m = 4; m < 8; ++m)
        #pragma unroll
        for (int n = 2; n < 4; ++n)
          acc[m][n] = mfma16(a[m][kq], b[n][kq], acc[m][n]);
    __builtin_amdgcn_s_setprio(0);
    __builtin_amdgcn_s_barrier();

    // ===== key-tile epilogue (every 16 K-tiles), latency-overlapped =====
    if ((T & 15) == 15) {
      const int it = T >> 4;
      const int bcol0 = (sub + 8 * it) * 256;
      const int keyb = bcol0 + wc * 64 + l15;
      #pragma unroll
      for (int mc = 0; mc < 4; ++mc) {
        // -- phase A: batch-prefetch adjacency + rowmax (overlapped loads)
        uint32_t A0[2][4], A1[2][4]; float RX[2][4]; int ROW[2][4];
        #pragma unroll
        for (int mm = 0; mm < 2; ++mm)
          #pragma unroll
          for (int j = 0; j < 4; ++j) {
            const int m = mc * 2 + mm;
            const int row = arow0 + wr * 128 + m * 16 + g4 + j;
            ROW[mm][j] = row;
            const uint32_t* ap = adjb + (size_t)row * (NROWS / 32) + (bcol0 >> 5) + wc * 2;
            A0[mm][j] = ap[0];
            A1[mm][j] = ap[1];
            RX[mm][j] = __int_as_float(rowmax[row]);   // stale-tolerant
          }
        // -- phase B: scores/masks/reduce; fire atomicMax; issue atomicAdds
        float SV[2][4][4]; float TH[2][4]; int BS[2][4];
        #pragma unroll
        for (int mm = 0; mm < 2; ++mm)
          #pragma unroll
          for (int j = 0; j < 4; ++j) {
            const int m = mc * 2 + mm;
            float rm = NEGBIG;
            #pragma unroll
            for (int n = 0; n < 4; ++n) {
              float v = fmaxf(acc[m][n][j], 0.f);
              uint32_t bit = ((n < 2 ? A0[mm][j] : A1[mm][j]) >> ((n & 1) * 16 + l15)) & 1u;
              float s = bit ? v : NEGBIG;
              SV[mm][j][n] = s;
              rm = fmaxf(rm, s);
            }
            rm = fmaxf(rm, __shfl_xor(rm, 1));
            rm = fmaxf(rm, __shfl_xor(rm, 2));
            rm = fmaxf(rm, __shfl_xor(rm, 4));
            rm = fmaxf(rm, __shfl_xor(rm, 8));
            const float mr = fmaxf(rm, RX[mm][j]);
            if (l15 == 0 && rm > RX[mm][j])
              atomicMax(rowmax + ROW[mm][j], __float_as_int(rm));
            TH[mm][j] = mr - EMIT_THR;
            int tot = 0;
            #pragma unroll
            for (int n = 0; n < 4; ++n)
              tot += __popcll(__ballot(SV[mm][j][n] > TH[mm][j]) & gm);
            BS[mm][j] = 0;
            if (l15 == 0 && tot > 0)
              BS[mm][j] = atomicAdd(cnts + ROW[mm][j], tot);
          }
        // -- phase C: re-ballot, place, store (atomic returns now landed)
        #pragma unroll
        for (int mm = 0; mm < 2; ++mm)
          #pragma unroll
          for (int j = 0; j < 4; ++j) {
            int base = __shfl(BS[mm][j], lane & 48);
            int pref = 0;
            #pragma unroll
            for (int n = 0; n < 4; ++n) {
              unsigned long long mk = __ballot(SV[mm][j][n] > TH[mm][j]);
              const int p = base + pref + __popcll(mk & gm & lmask);
              if ((SV[mm][j][n] > TH[mm][j]) && p < CAP)
                cand[(size_t)ROW[mm][j] * CAP + p] =
                    ((uint32_t)f2bf(SV[mm][j][n]) << 16) | (uint32_t)(keyb + n * 16);
              pref += __popcll(mk & gm);
            }
          }
      }
      #pragma unroll
      for (int m = 0; m < 8; ++m)
        #pragma unroll
        for (int n = 0; n < 4; ++n) acc[m][n] = f32x4{0.f, 0.f, 0.f, 0.f};
    }
  }
}

// ---------------------------------------------------------------------------
// adj (int32 0/1, 268 MB) -> bitmask (8 MB). BW-bound single pass.
// ---------------------------------------------------------------------------
__global__ __launch_bounds__(256) void adjpack_kernel(
    const int* __restrict__ adj, uint32_t* __restrict__ adjb)
{
  size_t w = (size_t)blockIdx.x * 256 + threadIdx.x;
  const int* src = adj + (w << 5);
  uint32_t m = 0;
  #pragma unroll
  for (int j = 0; j < 8; ++j) {
    i32x4 v = *(const i32x4*)(src + j * 4);
    m |= (v[0] > 0 ? 1u : 0u) << (j * 4)
       | (v[1] > 0 ? 1u : 0u) << (j * 4 + 1)
       | (v[2] > 0 ? 1u : 0u) << (j * 4 + 2)
       | (v[3] > 0 ? 1u : 0u) << (j * 4 + 3);
  }
  adjb[w] = m;
}

// ---------------------------------------------------------------------------
// Finalize: survivors (within SURV_THR of approx max) rescored exactly in
// fp32 from (fh+fl, gh+gl); tail stays approx in the denominator only.
// ---------------------------------------------------------------------------
__global__ __launch_bounds__(256) void finalize_kernel(
    const uint32_t* __restrict__ cand, const int* __restrict__ cnts,
    const u16* __restrict__ fh, const u16* __restrict__ fl,
    const u16* __restrict__ gh, const u16* __restrict__ gl,
    const u16* __restrict__ vh, float* __restrict__ out)
{
  const int row = blockIdx.x, tid = threadIdx.x, wv = tid >> 6, lane = tid & 63;
  __shared__ float sS[CAP];
  __shared__ int sK[CAP];
  __shared__ float sF[KDIM];
  __shared__ float sEx[MAXS];
  __shared__ int sKs[MAXS];
  __shared__ float red[4];
  __shared__ int nsig;
  int cnt = cnts[row]; cnt = cnt < CAP ? cnt : CAP;
  const int col = tid * 4;
  if (cnt <= 0) {
    f32x4 z = {0.f, 0.f, 0.f, 0.f};
    *(f32x4*)(out + (size_t)row * KDIM + col) = z;
    return;
  }
  if (tid == 0) nsig = 0;
  {
    us4 h = *(const us4*)(fh + (size_t)row * KDIM + col);
    us4 l = *(const us4*)(fl + (size_t)row * KDIM + col);
    #pragma unroll
    for (int j = 0; j < 4; ++j) sF[col + j] = bf2f(h[j]) + bf2f(l[j]);
  }
  for (int i = tid; i < cnt; i += 256) {
    uint32_t pk = cand[(size_t)row * CAP + i];
    sS[i] = bf2f((u16)(pk >> 16));
    sK[i] = (int)(pk & 0xFFFFu);
  }
  __syncthreads();
  float lm = NEGBIG;
  for (int i = tid; i < cnt; i += 256) lm = fmaxf(lm, sS[i]);
  #pragma unroll
  for (int d = 1; d < 64; d <<= 1) lm = fmaxf(lm, __shfl_xor(lm, d));
  if ((tid & 63) == 0) red[tid >> 6] = lm;
  __syncthreads();
  const float am = fmaxf(fmaxf(red[0], red[1]), fmaxf(red[2], red[3]));
  __syncthreads();
  for (int i = tid; i < cnt; i += 256) {
    if (sS[i] > am - SURV_THR) {
      int p = atomicAdd(&nsig, 1);
      if (p < MAXS) { sKs[p] = sK[i]; sS[i] = NEGBIG; }
    }
  }
  __syncthreads();
  const int ns = nsig < MAXS ? nsig : MAXS;
  for (int si = wv; si < ns; si += 4) {
    const int key = sKs[si];
    const u16* grh = gh + (size_t)key * KDIM + lane * 16;
    const u16* grl = gl + (size_t)key * KDIM + lane * 16;
    float d = 0.f;
    #pragma unroll
    for (int u = 0; u < 4; ++u) {
      us4 h = *(const us4*)(grh + u * 4);
      us4 l = *(const us4*)(grl + u * 4);
      #pragma unroll
      for (int j = 0; j < 4; ++j)
        d += (bf2f(h[j]) + bf2f(l[j])) * sF[lane * 16 + u * 4 + j];
    }
    #pragma unroll
    for (int dd = 1; dd < 64; dd <<= 1) d += __shfl_xor(d, dd);
    if (lane == 0) sEx[si] = fmaxf(d, 0.f);
  }
  __syncthreads();
  float em = NEGBIG;
  for (int i = tid; i < ns; i += 256) em = fmaxf(em, sEx[i]);
  #pragma unroll
  for (int d = 1; d < 64; d <<= 1) em = fmaxf(em, __shfl_xor(em, d));
  if ((tid & 63) == 0) red[tid >> 6] = em;
  __syncthreads();
  const float m = fmaxf(fmaxf(red[0], red[1]), fmaxf(red[2], red[3]));
  __syncthreads();
  float ls = 0.f;
  for (int i = tid; i < cnt; i += 256) {
    float s = sS[i];
    if (s > NEGBIG * 0.5f) ls += __expf(s - m);
  }
  for (int i = tid; i < ns; i += 256) ls += __expf(sEx[i] - m);
  #pragma unroll
  for (int d = 1; d < 64; d <<= 1) ls += __shfl_xor(ls, d);
  if ((tid & 63) == 0) red[tid >> 6] = ls;
  __syncthreads();
  const float inv = 1.f / (red[0] + red[1] + red[2] + red[3]);
  float a0 = 0.f, a1 = 0.f, a2 = 0.f, a3 = 0.f;
  const u16* vbase = vh + col;
  for (int i = 0; i < ns; ++i) {
    const float wt = __expf(sEx[i] - m) * inv;
    us4 vv = *(const us4*)(vbase + (size_t)sKs[i] * KDIM);
    a0 += wt * bf2f(vv[0]); a1 += wt * bf2f(vv[1]);
    a2 += wt * bf2f(vv[2]); a3 += wt * bf2f(vv[3]);
  }
  f32x4 o = {a0, a1, a2, a3};
  *(f32x4*)(out + (size_t)row * KDIM + col) = o;
}

// ---------------------------------------------------------------------------
// Transpose + hi/lo split of a [K][N] fp32 weight into [N][K] bf16 pair.
// ---------------------------------------------------------------------------
__global__ __launch_bounds__(256) void wsplit_kernel(
    const float* __restrict__ W, u16* __restrict__ th, u16* __restrict__ tl)
{
  __shared__ float tile[32][33];
  const int bx = blockIdx.x, by = blockIdx.y;
  const int tx = threadIdx.x & 31, ty = threadIdx.x >> 5;
  #pragma unroll
  for (int i = 0; i < 4; ++i) {
    int ky = ty + i * 8;
    tile[ky][tx] = W[(size_t)(by * 32 + ky) * KDIM + bx * 32 + tx];
  }
  __syncthreads();
  #pragma unroll
  for (int i = 0; i < 4; ++i) {
    int ny = ty + i * 8;
    float v = tile[tx][ny];
    u16 h = f2bf(v);
    th[(size_t)(bx * 32 + ny) * KDIM + by * 32 + tx] = h;
    tl[(size_t)(bx * 32 + ny) * KDIM + by * 32 + tx] = f2bf(v - bf2f(h));
  }
}

__global__ __launch_bounds__(256) void xsplit_kernel(
    const float* __restrict__ x, u16* __restrict__ xh, u16* __restrict__ xl)
{
  size_t i = ((size_t)blockIdx.x * 256 + threadIdx.x) * 4;
  f32x4 v = *(const f32x4*)(x + i);
  us4 h, l;
  #pragma unroll
  for (int j = 0; j < 4; ++j) {
    h[j] = f2bf(v[j]);
    l[j] = f2bf(v[j] - bf2f(h[j]));
  }
  *(us4*)(xh + i) = h;
  *(us4*)(xl + i) = l;
}

__global__ void ws_report(float* out, size_t n, float v) {
  for (size_t i = (size_t)blockIdx.x * blockDim.x + threadIdx.x; i < n;
       i += (size_t)gridDim.x * blockDim.x) out[i] = v;
}

extern "C" void kernel_launch(void* const* d_in, const int* in_sizes, int n_in,
                              void* d_out, int out_size, void* d_ws, size_t ws_size,
                              hipStream_t stream) {
  (void)in_sizes; (void)n_in;
  const float* x   = (const float*)d_in[0];
  const int*   adj = (const int*)d_in[1];
  const float* Wf  = (const float*)d_in[2];
  const float* bf_ = (const float*)d_in[3];
  const float* Wg  = (const float*)d_in[4];
  const float* bg_ = (const float*)d_in[5];
  const float* W   = (const float*)d_in[6];
  const float* bW_ = (const float*)d_in[7];

  char* p = (char*)d_ws;
  const size_t ND2 = (size_t)NROWS * KDIM * 2;
  const size_t W2  = (size_t)KDIM * KDIM * 2;
  u16* xh = (u16*)p;  p += ND2;
  u16* xl = (u16*)p;  p += ND2;
  u16* fh = (u16*)p;  p += ND2;
  u16* fl = (u16*)p;  p += ND2;
  u16* gh = (u16*)p;  p += ND2;
  u16* gl = (u16*)p;  p += ND2;
  u16* vh = (u16*)p;  p += ND2;
  u16* wfh = (u16*)p; p += W2;
  u16* wfl = (u16*)p; p += W2;
  u16* wgh = (u16*)p; p += W2;
  u16* wgl = (u16*)p; p += W2;
  u16* wh  = (u16*)p; p += W2;
  u16* wl  = (u16*)p; p += W2;
  uint32_t* cand = (uint32_t*)p; p += (size_t)NROWS * CAP * 4;
  int* cnts   = (int*)p; p += (size_t)NROWS * 4;
  int* rowmax = (int*)p; p += (size_t)NROWS * 4;
  const size_t need = (size_t)(p - (char*)d_ws);
  if (ws_size < need) {
    ws_report<<<256, 256, 0, stream>>>((float*)d_out, (size_t)out_size, (float)ws_size);
    return;
  }
  uint32_t* adjb = (uint32_t*)xl;   // aliases xl after pre-GEMMs are done

  auto kf = gemm_kernel<3, true>;
  auto kv = gemm_kernel<1, false>;
  hipFuncSetAttribute((const void*)kf, hipFuncAttributeMaxDynamicSharedMemorySize, 131072);
  hipFuncSetAttribute((const void*)kv, hipFuncAttributeMaxDynamicSharedMemorySize, 65536);
  hipFuncSetAttribute((const void*)scores_kernel, hipFuncAttributeMaxDynamicSharedMemorySize, 131072);

  hipMemsetAsync(cnts, 0, (size_t)NROWS * 8, stream);   // cnts + rowmax (0 == 0.0f)
  wsplit_kernel<<<dim3(32, 32), 256, 0, stream>>>(Wf, wfh, wfl);
  wsplit_kernel<<<dim3(32, 32), 256, 0, stream>>>(Wg, wgh, wgl);
  wsplit_kernel<<<dim3(32, 32), 256, 0, stream>>>(W, wh, wl);
  xsplit_kernel<<<(NROWS * KDIM) / (256 * 4), 256, 0, stream>>>(x, xh, xl);

  // f = x@Wf + bf, g = x@Wg + bg (split-3, hi+lo out), v = x@W + bW (1 pass)
  kf<<<dim3(64, 8), 512, 131072, stream>>>(xh, xl, wfh, wfl, bf_, fh, fl);
  kf<<<dim3(64, 8), 512, 131072, stream>>>(xh, xl, wgh, wgl, bg_, gh, gl);
  kv<<<dim3(64, 8), 512, 65536, stream>>>(xh, xl, wh, wl, bW_, vh, nullptr);
  adjpack_kernel<<<(NROWS * (NROWS / 32)) / 256, 256, 0, stream>>>(adj, adjb);
  // un-pinned counted-vmcnt 4-phase 256x256 scores sweep
  scores_kernel<<<dim3(256), 512, 131072, stream>>>(fh, gh, adjb, cand, cnts, rowmax);
  // exact rescoring of survivors + softmax + v gather
  finalize_kernel<<<NROWS, 256, 0, stream>>>(cand, cnts, fh, fl, gh, gl, vh,
                                             (float*)d_out);
}